// Round 8
// baseline (1717.897 us; speedup 1.0000x reference)
//
#include <hip/hip_runtime.h>
#include <hip/hip_bf16.h>

// Problem constants
#define B_ 128
#define S_ 128
#define W_ 16
#define V_ 128
#define H_ 512
#define L_ 64

typedef _Float16 f16x8 __attribute__((ext_vector_type(8)));
typedef float f32x4 __attribute__((ext_vector_type(4)));

__device__ __forceinline__ float sigm(float v) { return 1.0f / (1.0f + __expf(-v)); }
__device__ __forceinline__ float tanhf_(float v) { return 1.0f - 2.0f / (1.0f + __expf(2.0f * v)); }

__device__ __forceinline__ unsigned short f16bits(_Float16 h) {
    return __builtin_bit_cast(unsigned short, h);
}

// ---------------------------------------------------------------------------
// Workspace layout (bytes):
//   hbuf  u32 packed(hi,lo) [par2][dir2][128][512] @ 0        (1048576)
//   slots u32 [16 chains][4 blocks][32 pad]        @ 1048576  (8192)
//   flag  i32                                      @ 1056768  (64)
//   xhi   u16 [128][128][128]                      @ 1056832  (4194304)
//   xlo   u16 [128][128][128]                      @ 5251136  (4194304)
//   whalf f16 [1966080]                            @ 9445440  (3932160)
//         [whhf 786432 | whhb 786432 | wihf 196608 | wihb 196608]
//   smallF f32 [71745]                             @ 13377600 (286980)
//         [bihf 1536|bhhf 1536|bihb 1536|bhhb 1536|wlin 65536|blin 64|fg 1]
//   Ycat  f16 [128][128][1024]                     @ 13664640 (33554432) -> ends 47219072
// ---------------------------------------------------------------------------
#define OFF_SLOT  1048576
#define OFF_FLAG  1056768
#define OFF_XHI   1056832
#define OFF_XLO   5251136
#define OFF_WH    9445440
#define OFF_SMALL 13377600
#define OFF_YCAT  13664640

// Runtime input-dtype detection (insurance): low-16 exponent-field vote.
__global__ void detect_kernel(const unsigned* __restrict__ w, int* __restrict__ flag) {
    __shared__ int sv[256];
    int tid = threadIdx.x;
    unsigned word = w[tid];
    unsigned e = (word >> 7) & 0xFFu;
    sv[tid] = (e >= 64u && e <= 126u) ? 1 : 0;
    __syncthreads();
    for (int s = 128; s > 0; s >>= 1) {
        if (tid < s) sv[tid] += sv[tid + s];
        __syncthreads();
    }
    if (tid == 0) *flag = (sv[0] >= 160) ? 1 : 0;  // 1 = inputs are bf16
}

// Canonicalize the 4 big weight matrices into packed fp16 (RTN) in ws.
__global__ void prep_whalf(const void* __restrict__ whhf, const void* __restrict__ whhb,
                           const void* __restrict__ wihf, const void* __restrict__ wihb,
                           _Float16* __restrict__ dst, const int* __restrict__ flag) {
    int i = blockIdx.x * 256 + threadIdx.x;  // grid covers 1966080 exactly
    const void* src;
    int off;
    if (i < 786432)       { src = whhf; off = i; }
    else if (i < 1572864) { src = whhb; off = i - 786432; }
    else if (i < 1769472) { src = wihf; off = i - 1572864; }
    else                  { src = wihb; off = i - 1769472; }
    float v = (*flag) ? __bfloat162float(((const __hip_bfloat16*)src)[off])
                      : ((const float*)src)[off];
    dst[i] = (_Float16)v;
}

// Canonicalize biases + W_lin + b_lin + forget into fp32 in ws.
__global__ void prep_small(const void* __restrict__ bihf, const void* __restrict__ bhhf,
                           const void* __restrict__ bihb, const void* __restrict__ bhhb,
                           const void* __restrict__ wlin, const void* __restrict__ blin,
                           const void* __restrict__ fg,
                           float* __restrict__ dst, const int* __restrict__ flag) {
    int i = blockIdx.x * 256 + threadIdx.x;
    if (i >= 71745) return;
    const void* src;
    int off;
    if (i < 1536)       { src = bihf; off = i; }
    else if (i < 3072)  { src = bhhf; off = i - 1536; }
    else if (i < 4608)  { src = bihb; off = i - 3072; }
    else if (i < 6144)  { src = bhhb; off = i - 4608; }
    else if (i < 71680) { src = wlin; off = i - 6144; }
    else if (i < 71744) { src = blin; off = i - 71680; }
    else                { src = fg;   off = 0; }
    float v = (*flag) ? __bfloat162float(((const __hip_bfloat16*)src)[off])
                      : ((const float*)src)[off];
    dst[i] = v;
}

// FOFE -> split hi/lo fp16 planes. 256 thr = 2 positions per block.
__global__ void fofe_kernel(const int* __restrict__ chars,
                            const float* __restrict__ fg,
                            unsigned short* __restrict__ xhi,
                            unsigned short* __restrict__ xlo) {
    __shared__ int cS[2][W_];
    int tid = threadIdx.x;
    int sub = tid >> 7;        // 0..1
    int v = tid & 127;
    int bi = blockIdx.x * 2 + sub;  // b*S + s
    if (v < W_) cS[sub][v] = chars[bi * W_ + v];
    __syncthreads();
    float f = fg[0];
    float wt[W_];
    float cur = 1.0f;
#pragma unroll
    for (int w = W_ - 1; w >= 0; --w) {
        bool m = (cS[sub][w] != 0);
        wt[w] = m ? cur : 0.0f;
        if (m) cur *= f;
    }
    float acc = 0.0f;
#pragma unroll
    for (int w = 0; w < W_; ++w) acc += (cS[sub][w] == v) ? wt[w] : 0.0f;
    _Float16 hi = (_Float16)acc;
    _Float16 lo = (_Float16)(acc - (float)hi);
    xhi[(size_t)bi * V_ + v] = f16bits(hi);
    xlo[(size_t)bi * V_ + v] = f16bits(lo);
}

// ---------------------------------------------------------------------------
// Persistent bidirectional GRU, fp16 hi/lo, fp32 accumulate.
// 16 chains x 4 blocks x 512 thr (8 waves). chain = blockIdx&15: blocks
// {c,c+16,c+32,c+48} -> one XCD under %8 round-robin. Wave owns 16 j x 3
// gates; weights persistent in VGPRs. h exchange: packed (hi,lo) u32, relaxed
// agent-scope atomic stores (write-through) / u64 loads (cache-bypass).
// Barrier: per-block flag slots (128B apart, plain release stores - no RMW
// bouncing), wave-0 lanes 0..3 poll all slots in parallel. Ycat stores issue
// AFTER the arrival post so they drain during the next step's spin.
// ---------------------------------------------------------------------------
__launch_bounds__(512, 1)
__global__ void gru_kernel(const int* __restrict__ lengths,
                           const _Float16* __restrict__ wh,
                           const float* __restrict__ biasF,
                           const unsigned short* __restrict__ xhi,
                           const unsigned short* __restrict__ xlo,
                           unsigned* __restrict__ hbuf,
                           unsigned* __restrict__ slots,
                           _Float16* __restrict__ Ycat) {
    constexpr int RSTR = 656;  // 640 + 16 pad halves (0 conflicts measured r5/r7)
    __shared__ _Float16 Ahi[16 * RSTR];
    __shared__ _Float16 Alo[16 * RSTR];
    __shared__ int lenS[16];

    const int tid = threadIdx.x;
    const int chain = blockIdx.x & 15;
    const int blk = blockIdx.x >> 4;    // 0..3
    const int d = chain & 1;
    const int bg = chain >> 1;
    const int b0 = bg * 16;
    const int wave = tid >> 6;          // 0..7
    const int lane = tid & 63;
    const int quad = lane >> 4;
    const int col = lane & 15;
    const int j0w = (blk * 8 + wave) * 16;  // 0..496

    const _Float16* Whh = wh + (d ? 786432 : 0);
    const _Float16* Wih = wh + 1572864 + (d ? 196608 : 0);
    const float* bih = biasF + (d ? 3072 : 0);
    const float* bhh = biasF + 1536 + (d ? 3072 : 0);

    if (tid < 16) lenS[tid] = lengths[b0 + tid];
    __syncthreads();

    const int g_r = j0w + col;  // r row; z = 512+g_r; n = 1024+g_r

    // Persistent B fragments: lane holds W[g][kk*32 + quad*8 + 0..7]
    f16x8 br[20], bz[20], bn[20];
#pragma unroll
    for (int kk = 0; kk < 16; ++kk) {
        int k = kk * 32 + quad * 8;
        br[kk] = *(const f16x8*)(Whh + (size_t)(g_r)*H_ + k);
        bz[kk] = *(const f16x8*)(Whh + (size_t)(512 + g_r) * H_ + k);
        bn[kk] = *(const f16x8*)(Whh + (size_t)(1024 + g_r) * H_ + k);
    }
#pragma unroll
    for (int kk = 16; kk < 20; ++kk) {
        int k = (kk - 16) * 32 + quad * 8;
        br[kk] = *(const f16x8*)(Wih + (size_t)(g_r)*V_ + k);
        bz[kk] = *(const f16x8*)(Wih + (size_t)(512 + g_r) * V_ + k);
        bn[kk] = *(const f16x8*)(Wih + (size_t)(1024 + g_r) * V_ + k);
    }

    const float bias_r = bih[g_r] + bhh[g_r];
    const float bias_z = bih[512 + g_r] + bhh[512 + g_r];
    const float bihn = bih[1024 + g_r];
    const float bhhn = bhh[1024 + g_r];

    int len4[4];
#pragma unroll
    for (int i = 0; i < 4; ++i) len4[i] = lenS[quad * 4 + i];
    const int maxlen = lenS[0];  // lengths sorted descending

    float h_own[4] = {0.f, 0.f, 0.f, 0.f};  // fp32 master state (b=quad*4+i, j=col)

    const _Float16* arh = &Ahi[col * RSTR + quad * 8];
    const _Float16* arl = &Alo[col * RSTR + quad * 8];

    // x staging (tid<256): 16 rows x 16 chunks of 8 halves
    const int xb = (tid & 255) >> 4;
    const int xv8 = (tid & 15) * 8;

    for (int t = 0; t < S_; ++t) {
        if (t < maxlen) {
            const int par = t & 1;
            // ---- x loads (plain cached, RO; issued before barrier) ----
            int4 xh4, xl4;
            if (tid < 256) {
                int lxb = lenS[xb];
                int sxb = d ? max(0, lxb - 1 - t) : t;
                xh4 = *(const int4*)(xhi + ((size_t)(b0 + xb) * S_ + sxb) * V_ + xv8);
                xl4 = *(const int4*)(xlo + ((size_t)(b0 + xb) * S_ + sxb) * V_ + xv8);
            }
            // ---- chain barrier: all 4 blocks posted step t-1 (parallel poll) ----
            if (t > 0) {
                if (tid < 64) {
                    unsigned spins = 0;
                    while (true) {
                        unsigned v = 0;
                        if (lane < 4)
                            v = __hip_atomic_load(&slots[(chain * 4 + lane) * 32],
                                                  __ATOMIC_ACQUIRE, __HIP_MEMORY_SCOPE_AGENT);
                        bool ok = (lane < 4) ? (v >= (unsigned)t) : true;
                        if (__all(ok)) break;
                        __builtin_amdgcn_s_sleep(1);
                        if (++spins > 50000000u) break;  // deadlock -> visible timeout
                    }
                }
                __syncthreads();  // join spin; also WAR (step t-1 LDS reads done)
            }
            // ---- h loads: cache-bypass u64 atomics (2 packed elems each) ----
            // 4096 chunks = 16 rows x 256 chunks(2 u32); 8 per thread
            const unsigned* hrp = hbuf + ((size_t)(par * 2 + d) * B_ + b0) * H_;
            unsigned long long hv[8];
#pragma unroll
            for (int i = 0; i < 8; ++i) {
                int c = tid + i * 512;
                int b = c >> 8;
                int k2 = (c & 255) * 2;
                hv[i] = __hip_atomic_load((const unsigned long long*)(hrp + (size_t)b * H_ + k2),
                                          __ATOMIC_RELAXED, __HIP_MEMORY_SCOPE_AGENT);
            }
            // ---- stage x into LDS (values ready from pre-barrier loads) ----
            if (tid < 256) {
                *(int4*)&Ahi[xb * RSTR + 512 + xv8] = xh4;
                *(int4*)&Alo[xb * RSTR + 512 + xv8] = xl4;
            }
            // ---- unpack h and stage into LDS ----
#pragma unroll
            for (int i = 0; i < 8; ++i) {
                int c = tid + i * 512;
                int b = c >> 8;
                int k2 = (c & 255) * 2;
                unsigned p0 = (unsigned)hv[i];
                unsigned p1 = (unsigned)(hv[i] >> 32);
                unsigned hi2 = (p0 & 0xffffu) | (p1 << 16);
                unsigned lo2 = (p0 >> 16) | (p1 & 0xffff0000u);
                *(unsigned*)&Ahi[b * RSTR + k2] = hi2;
                *(unsigned*)&Alo[b * RSTR + k2] = lo2;
            }
            __syncthreads();

            // ---- MFMA: hw = (h_hi + h_lo) @ W^T (fp16 in, fp32 acc) ----
            f32x4 accr = {0.f, 0.f, 0.f, 0.f};
            f32x4 accz = {0.f, 0.f, 0.f, 0.f};
            f32x4 acchn = {0.f, 0.f, 0.f, 0.f};
            f32x4 accxn = {0.f, 0.f, 0.f, 0.f};
#pragma unroll
            for (int kk = 0; kk < 16; ++kk) {
                f16x8 ah = *(const f16x8*)(arh + kk * 32);
                f16x8 al = *(const f16x8*)(arl + kk * 32);
                accr = __builtin_amdgcn_mfma_f32_16x16x32_f16(ah, br[kk], accr, 0, 0, 0);
                accr = __builtin_amdgcn_mfma_f32_16x16x32_f16(al, br[kk], accr, 0, 0, 0);
                accz = __builtin_amdgcn_mfma_f32_16x16x32_f16(ah, bz[kk], accz, 0, 0, 0);
                accz = __builtin_amdgcn_mfma_f32_16x16x32_f16(al, bz[kk], accz, 0, 0, 0);
                acchn = __builtin_amdgcn_mfma_f32_16x16x32_f16(ah, bn[kk], acchn, 0, 0, 0);
                acchn = __builtin_amdgcn_mfma_f32_16x16x32_f16(al, bn[kk], acchn, 0, 0, 0);
            }
#pragma unroll
            for (int kk = 16; kk < 20; ++kk) {
                f16x8 ah = *(const f16x8*)(arh + 512 + (kk - 16) * 32);
                f16x8 al = *(const f16x8*)(arl + 512 + (kk - 16) * 32);
                accr = __builtin_amdgcn_mfma_f32_16x16x32_f16(ah, br[kk], accr, 0, 0, 0);
                accr = __builtin_amdgcn_mfma_f32_16x16x32_f16(al, br[kk], accr, 0, 0, 0);
                accz = __builtin_amdgcn_mfma_f32_16x16x32_f16(ah, bz[kk], accz, 0, 0, 0);
                accz = __builtin_amdgcn_mfma_f32_16x16x32_f16(al, bz[kk], accz, 0, 0, 0);
                accxn = __builtin_amdgcn_mfma_f32_16x16x32_f16(ah, bn[kk], accxn, 0, 0, 0);
                accxn = __builtin_amdgcn_mfma_f32_16x16x32_f16(al, bn[kk], accxn, 0, 0, 0);
            }

            // ---- gates + state update + packed h stores ----
            unsigned* hwp = hbuf + ((size_t)((1 - par) * 2 + d) * B_ + b0) * H_;
            float yv[4];
            int so4[4];
#pragma unroll
            for (int i = 0; i < 4; ++i) {
                int bl = quad * 4 + i;
                float r = sigm(accr[i] + bias_r);
                float zg = sigm(accz[i] + bias_z);
                float ng = tanhf_((accxn[i] + bihn) + r * (acchn[i] + bhhn));
                float hcand = (1.0f - zg) * ng + zg * h_own[i];
                bool m = (t < len4[i]);
                yv[i] = m ? hcand : 0.0f;
                h_own[i] = m ? hcand : h_own[i];
                _Float16 hhi = (_Float16)h_own[i];
                _Float16 hlo = (_Float16)(h_own[i] - (float)hhi);
                unsigned packed = (unsigned)f16bits(hhi) | ((unsigned)f16bits(hlo) << 16);
                __hip_atomic_store(hwp + (size_t)bl * H_ + j0w + col, packed,
                                   __ATOMIC_RELAXED, __HIP_MEMORY_SCOPE_AGENT);
                so4[i] = (d && m) ? (len4[i] - 1 - t) : t;
            }
            __syncthreads();  // vmcnt(0): h stores at coherence point
            if (tid == 0)
                __hip_atomic_store(&slots[(chain * 4 + blk) * 32], (unsigned)(t + 1),
                                   __ATOMIC_RELEASE, __HIP_MEMORY_SCOPE_AGENT);
            // ---- Ycat stores AFTER arrival: drain overlaps next step's spin ----
#pragma unroll
            for (int i = 0; i < 4; ++i) {
                int bl = quad * 4 + i;
                Ycat[((size_t)(b0 + bl) * S_ + so4[i]) * 1024 + d * 512 + j0w + col] =
                    (_Float16)yv[i];
            }
        } else {
            // whole group masked: zeros at s_out = t; no barrier traffic
#pragma unroll
            for (int i = 0; i < 4; ++i) {
                int bl = quad * 4 + i;
                Ycat[((size_t)(b0 + bl) * S_ + t) * 1024 + d * 512 + j0w + col] = (_Float16)0.0f;
            }
        }
    }
}

// Final linear: out[b,s,l] = b_lin[l] + sum_c Ycat[b,s,c] * Wf[l,c]  (fp32 out)
__global__ void lin_kernel(const _Float16* __restrict__ Ycat, const float* __restrict__ Wf,
                           const float* __restrict__ blinF, float* __restrict__ out) {
    int tid = threadIdx.x;
    int p_loc = tid >> 4, lq = tid & 15;
    int pos = blockIdx.x * 16 + p_loc;
    const _Float16* yrow = Ycat + (size_t)pos * 1024;
    int l0 = lq * 4;
    const float* w0 = Wf + (size_t)(l0 + 0) * 1024;
    const float* w1 = Wf + (size_t)(l0 + 1) * 1024;
    const float* w2 = Wf + (size_t)(l0 + 2) * 1024;
    const float* w3 = Wf + (size_t)(l0 + 3) * 1024;
    float a0 = 0.f, a1 = 0.f, a2 = 0.f, a3 = 0.f;
    for (int c = 0; c < 1024; c += 8) {
        f16x8 y8 = *(const f16x8*)(yrow + c);
#pragma unroll
        for (int e = 0; e < 8; ++e) {
            float y = (float)y8[e];
            a0 = fmaf(y, w0[c + e], a0);
            a1 = fmaf(y, w1[c + e], a1);
            a2 = fmaf(y, w2[c + e], a2);
            a3 = fmaf(y, w3[c + e], a3);
        }
    }
    size_t ob = (size_t)pos * L_ + l0;
    out[ob + 0] = a0 + blinF[l0 + 0];
    out[ob + 1] = a1 + blinF[l0 + 1];
    out[ob + 2] = a2 + blinF[l0 + 2];
    out[ob + 3] = a3 + blinF[l0 + 3];
}

extern "C" void kernel_launch(void* const* d_in, const int* in_sizes, int n_in,
                              void* d_out, int out_size, void* d_ws, size_t ws_size,
                              hipStream_t stream) {
    const int* chars = (const int*)d_in[0];
    const int* lengths = (const int*)d_in[1];
    const void* forget = d_in[2];
    const void* Wihf = d_in[3];
    const void* Whhf = d_in[4];
    const void* bihf = d_in[5];
    const void* bhhf = d_in[6];
    const void* Wihb = d_in[7];
    const void* Whhb = d_in[8];
    const void* bihb = d_in[9];
    const void* bhhb = d_in[10];
    const void* Wlin = d_in[11];
    const void* blin = d_in[12];
    float* out = (float*)d_out;

    char* ws = (char*)d_ws;
    unsigned* hbuf = (unsigned*)(ws + 0);
    unsigned* slots = (unsigned*)(ws + OFF_SLOT);
    int* flag = (int*)(ws + OFF_FLAG);
    unsigned short* xhi = (unsigned short*)(ws + OFF_XHI);
    unsigned short* xlo = (unsigned short*)(ws + OFF_XLO);
    _Float16* whalf = (_Float16*)(ws + OFF_WH);
    float* smallF = (float*)(ws + OFF_SMALL);
    _Float16* Ycat = (_Float16*)(ws + OFF_YCAT);

    // zero h state (both parities) + slots + flag
    (void)hipMemsetAsync(ws, 0, OFF_XHI, stream);

    hipLaunchKernelGGL(detect_kernel, dim3(1), dim3(256), 0, stream,
                       (const unsigned*)Whhf, flag);
    hipLaunchKernelGGL(prep_whalf, dim3(1966080 / 256), dim3(256), 0, stream,
                       Whhf, Whhb, Wihf, Wihb, whalf, flag);
    hipLaunchKernelGGL(prep_small, dim3(281), dim3(256), 0, stream,
                       bihf, bhhf, bihb, bhhb, Wlin, blin, forget, smallF, flag);
    hipLaunchKernelGGL(fofe_kernel, dim3(B_ * S_ / 2), dim3(256), 0, stream,
                       chars, smallF + 71744, xhi, xlo);

    // 16 chains x 4 blocks x 512 threads; per-block slot barrier, no RMW.
    hipLaunchKernelGGL(gru_kernel, dim3(64), dim3(512), 0, stream,
                       lengths, whalf, smallF, xhi, xlo, hbuf, slots, Ycat);

    hipLaunchKernelGGL(lin_kernel, dim3(B_ * S_ / 16), dim3(256), 0, stream,
                       Ycat, smallF + 6144, smallF + 71680, out);
}

// Round 9
// 1283.363 us; speedup vs baseline: 1.3386x; 1.3386x over previous
//
#include <hip/hip_runtime.h>
#include <hip/hip_bf16.h>

// Problem constants
#define B_ 128
#define S_ 128
#define W_ 16
#define V_ 128
#define H_ 512
#define L_ 64

typedef _Float16 f16x8 __attribute__((ext_vector_type(8)));
typedef float f32x4 __attribute__((ext_vector_type(4)));

__device__ __forceinline__ float sigm(float v) { return 1.0f / (1.0f + __expf(-v)); }
__device__ __forceinline__ float tanhf_(float v) { return 1.0f - 2.0f / (1.0f + __expf(2.0f * v)); }

__device__ __forceinline__ unsigned short f16bits(_Float16 h) {
    return __builtin_bit_cast(unsigned short, h);
}

// ---------------------------------------------------------------------------
// Workspace layout (bytes):
//   hbuf  u32 packed(hi,lo) [par2][dir2][128][512] @ 0        (1048576)
//   slots u32 [16 chains][8 blocks][32 pad]        @ 1048576  (16384)
//   flag  i32                                      @ 1064960  (64)
//   xhi   u16 [128][128][128]                      @ 1065024  (4194304)
//   xlo   u16 [128][128][128]                      @ 5259328  (4194304)
//   whalf f16 [1966080]                            @ 9453632  (3932160)
//         [whhf 786432 | whhb 786432 | wihf 196608 | wihb 196608]
//   smallF f32 [71745]                             @ 13385792 (287040)
//         [bihf 1536|bhhf 1536|bihb 1536|bhhb 1536|wlin 65536|blin 64|fg 1]
//   Ycat  f16 [128][128][1024]                     @ 13672832 (33554432) -> ends 47227264
// ---------------------------------------------------------------------------
#define OFF_SLOT  1048576
#define OFF_FLAG  1064960
#define OFF_XHI   1065024
#define OFF_XLO   5259328
#define OFF_WH    9453632
#define OFF_SMALL 13385792
#define OFF_YCAT  13672832

// Runtime input-dtype detection (insurance): low-16 exponent-field vote.
__global__ void detect_kernel(const unsigned* __restrict__ w, int* __restrict__ flag) {
    __shared__ int sv[256];
    int tid = threadIdx.x;
    unsigned word = w[tid];
    unsigned e = (word >> 7) & 0xFFu;
    sv[tid] = (e >= 64u && e <= 126u) ? 1 : 0;
    __syncthreads();
    for (int s = 128; s > 0; s >>= 1) {
        if (tid < s) sv[tid] += sv[tid + s];
        __syncthreads();
    }
    if (tid == 0) *flag = (sv[0] >= 160) ? 1 : 0;  // 1 = inputs are bf16
}

// Canonicalize the 4 big weight matrices into packed fp16 (RTN) in ws.
__global__ void prep_whalf(const void* __restrict__ whhf, const void* __restrict__ whhb,
                           const void* __restrict__ wihf, const void* __restrict__ wihb,
                           _Float16* __restrict__ dst, const int* __restrict__ flag) {
    int i = blockIdx.x * 256 + threadIdx.x;  // grid covers 1966080 exactly
    const void* src;
    int off;
    if (i < 786432)       { src = whhf; off = i; }
    else if (i < 1572864) { src = whhb; off = i - 786432; }
    else if (i < 1769472) { src = wihf; off = i - 1572864; }
    else                  { src = wihb; off = i - 1769472; }
    float v = (*flag) ? __bfloat162float(((const __hip_bfloat16*)src)[off])
                      : ((const float*)src)[off];
    dst[i] = (_Float16)v;
}

// Canonicalize biases + W_lin + b_lin + forget into fp32 in ws.
__global__ void prep_small(const void* __restrict__ bihf, const void* __restrict__ bhhf,
                           const void* __restrict__ bihb, const void* __restrict__ bhhb,
                           const void* __restrict__ wlin, const void* __restrict__ blin,
                           const void* __restrict__ fg,
                           float* __restrict__ dst, const int* __restrict__ flag) {
    int i = blockIdx.x * 256 + threadIdx.x;
    if (i >= 71745) return;
    const void* src;
    int off;
    if (i < 1536)       { src = bihf; off = i; }
    else if (i < 3072)  { src = bhhf; off = i - 1536; }
    else if (i < 4608)  { src = bihb; off = i - 3072; }
    else if (i < 6144)  { src = bhhb; off = i - 4608; }
    else if (i < 71680) { src = wlin; off = i - 6144; }
    else if (i < 71744) { src = blin; off = i - 71680; }
    else                { src = fg;   off = 0; }
    float v = (*flag) ? __bfloat162float(((const __hip_bfloat16*)src)[off])
                      : ((const float*)src)[off];
    dst[i] = v;
}

// FOFE -> split hi/lo fp16 planes. 256 thr = 2 positions per block.
__global__ void fofe_kernel(const int* __restrict__ chars,
                            const float* __restrict__ fg,
                            unsigned short* __restrict__ xhi,
                            unsigned short* __restrict__ xlo) {
    __shared__ int cS[2][W_];
    int tid = threadIdx.x;
    int sub = tid >> 7;        // 0..1
    int v = tid & 127;
    int bi = blockIdx.x * 2 + sub;  // b*S + s
    if (v < W_) cS[sub][v] = chars[bi * W_ + v];
    __syncthreads();
    float f = fg[0];
    float wt[W_];
    float cur = 1.0f;
#pragma unroll
    for (int w = W_ - 1; w >= 0; --w) {
        bool m = (cS[sub][w] != 0);
        wt[w] = m ? cur : 0.0f;
        if (m) cur *= f;
    }
    float acc = 0.0f;
#pragma unroll
    for (int w = 0; w < W_; ++w) acc += (cS[sub][w] == v) ? wt[w] : 0.0f;
    _Float16 hi = (_Float16)acc;
    _Float16 lo = (_Float16)(acc - (float)hi);
    xhi[(size_t)bi * V_ + v] = f16bits(hi);
    xlo[(size_t)bi * V_ + v] = f16bits(lo);
}

// ---------------------------------------------------------------------------
// Persistent bidirectional GRU, fp16 hi/lo, fp32 accumulate.
// r7 topology (measured 800us): 16 chains x 8 blocks x 256 thr (4 waves,
// 1 wave/SIMD, VGPR headroom for 240-reg persistent weights). chain =
// blockIdx&15: blocks {c,c+16,..} -> one XCD under %8 round-robin.
// r8 improvements kept: per-block slot flags (plain release STORES, no RMW
// line bouncing; wave-0 lanes 0..7 poll all 8 slots in parallel), packed
// (hi,lo) u32 h exchange (4 stores/thread), Ycat stores after the arrival
// post so their drain overlaps the next step's spin.
// ---------------------------------------------------------------------------
__launch_bounds__(256, 1)
__global__ void gru_kernel(const int* __restrict__ lengths,
                           const _Float16* __restrict__ wh,
                           const float* __restrict__ biasF,
                           const unsigned short* __restrict__ xhi,
                           const unsigned short* __restrict__ xlo,
                           unsigned* __restrict__ hbuf,
                           unsigned* __restrict__ slots,
                           _Float16* __restrict__ Ycat) {
    constexpr int RSTR = 656;  // 640 + 16 pad halves (0 conflicts measured r5/r7)
    __shared__ _Float16 Ahi[16 * RSTR];
    __shared__ _Float16 Alo[16 * RSTR];
    __shared__ int lenS[16];

    const int tid = threadIdx.x;
    const int chain = blockIdx.x & 15;
    const int blk = blockIdx.x >> 4;    // 0..7
    const int d = chain & 1;
    const int bg = chain >> 1;
    const int b0 = bg * 16;
    const int wave = tid >> 6;          // 0..3
    const int lane = tid & 63;
    const int quad = lane >> 4;
    const int col = lane & 15;
    const int j0w = (blk * 4 + wave) * 16;  // 0..496

    const _Float16* Whh = wh + (d ? 786432 : 0);
    const _Float16* Wih = wh + 1572864 + (d ? 196608 : 0);
    const float* bih = biasF + (d ? 3072 : 0);
    const float* bhh = biasF + 1536 + (d ? 3072 : 0);

    if (tid < 16) lenS[tid] = lengths[b0 + tid];
    __syncthreads();

    const int g_r = j0w + col;  // r row; z = 512+g_r; n = 1024+g_r

    // Persistent B fragments: lane holds W[g][kk*32 + quad*8 + 0..7]
    f16x8 br[20], bz[20], bn[20];
#pragma unroll
    for (int kk = 0; kk < 16; ++kk) {
        int k = kk * 32 + quad * 8;
        br[kk] = *(const f16x8*)(Whh + (size_t)(g_r)*H_ + k);
        bz[kk] = *(const f16x8*)(Whh + (size_t)(512 + g_r) * H_ + k);
        bn[kk] = *(const f16x8*)(Whh + (size_t)(1024 + g_r) * H_ + k);
    }
#pragma unroll
    for (int kk = 16; kk < 20; ++kk) {
        int k = (kk - 16) * 32 + quad * 8;
        br[kk] = *(const f16x8*)(Wih + (size_t)(g_r)*V_ + k);
        bz[kk] = *(const f16x8*)(Wih + (size_t)(512 + g_r) * V_ + k);
        bn[kk] = *(const f16x8*)(Wih + (size_t)(1024 + g_r) * V_ + k);
    }

    const float bias_r = bih[g_r] + bhh[g_r];
    const float bias_z = bih[512 + g_r] + bhh[512 + g_r];
    const float bihn = bih[1024 + g_r];
    const float bhhn = bhh[1024 + g_r];

    int len4[4];
#pragma unroll
    for (int i = 0; i < 4; ++i) len4[i] = lenS[quad * 4 + i];
    const int maxlen = lenS[0];  // lengths sorted descending

    float h_own[4] = {0.f, 0.f, 0.f, 0.f};  // fp32 master state (b=quad*4+i, j=col)

    const _Float16* arh = &Ahi[col * RSTR + quad * 8];
    const _Float16* arl = &Alo[col * RSTR + quad * 8];

    // x staging: 16 rows x 16 chunks of 8 halves (int4 per plane per thread)
    const int xb = tid >> 4;
    const int xv8 = (tid & 15) * 8;

    for (int t = 0; t < S_; ++t) {
        if (t < maxlen) {
            const int par = t & 1;
            // ---- x loads (plain cached, RO; issued before barrier) ----
            int lxb = lenS[xb];
            int sxb = d ? max(0, lxb - 1 - t) : t;
            int4 xh4 = *(const int4*)(xhi + ((size_t)(b0 + xb) * S_ + sxb) * V_ + xv8);
            int4 xl4 = *(const int4*)(xlo + ((size_t)(b0 + xb) * S_ + sxb) * V_ + xv8);
            // ---- chain barrier: all 8 blocks posted step t-1 (parallel poll) ----
            if (t > 0) {
                if (tid < 64) {
                    unsigned spins = 0;
                    while (true) {
                        unsigned v = (unsigned)t;
                        if (lane < 8)
                            v = __hip_atomic_load(&slots[(chain * 8 + lane) * 32],
                                                  __ATOMIC_ACQUIRE, __HIP_MEMORY_SCOPE_AGENT);
                        if (__all(v >= (unsigned)t)) break;
                        __builtin_amdgcn_s_sleep(1);
                        if (++spins > 50000000u) break;  // deadlock -> visible timeout
                    }
                }
                __syncthreads();  // join spin; also WAR (step t-1 LDS reads done)
            }
            // ---- h loads: cache-bypass u64 atomics (2 packed elems each) ----
            // 4096 chunks = 16 rows x 256 chunks(2 u32); 16 per thread
            const unsigned* hrp = hbuf + ((size_t)(par * 2 + d) * B_ + b0) * H_;
            unsigned long long hv[16];
#pragma unroll
            for (int i = 0; i < 16; ++i) {
                int c = tid + i * 256;
                int b = c >> 8;
                int k2 = (c & 255) * 2;
                hv[i] = __hip_atomic_load((const unsigned long long*)(hrp + (size_t)b * H_ + k2),
                                          __ATOMIC_RELAXED, __HIP_MEMORY_SCOPE_AGENT);
            }
            // ---- stage x into LDS (values ready from pre-barrier loads) ----
            *(int4*)&Ahi[xb * RSTR + 512 + xv8] = xh4;
            *(int4*)&Alo[xb * RSTR + 512 + xv8] = xl4;
            // ---- unpack h and stage into LDS ----
#pragma unroll
            for (int i = 0; i < 16; ++i) {
                int c = tid + i * 256;
                int b = c >> 8;
                int k2 = (c & 255) * 2;
                unsigned p0 = (unsigned)hv[i];
                unsigned p1 = (unsigned)(hv[i] >> 32);
                unsigned hi2 = (p0 & 0xffffu) | (p1 << 16);
                unsigned lo2 = (p0 >> 16) | (p1 & 0xffff0000u);
                *(unsigned*)&Ahi[b * RSTR + k2] = hi2;
                *(unsigned*)&Alo[b * RSTR + k2] = lo2;
            }
            __syncthreads();

            // ---- MFMA: hw = (h_hi + h_lo) @ W^T (fp16 in, fp32 acc) ----
            f32x4 accr = {0.f, 0.f, 0.f, 0.f};
            f32x4 accz = {0.f, 0.f, 0.f, 0.f};
            f32x4 acchn = {0.f, 0.f, 0.f, 0.f};
            f32x4 accxn = {0.f, 0.f, 0.f, 0.f};
#pragma unroll
            for (int kk = 0; kk < 16; ++kk) {
                f16x8 ah = *(const f16x8*)(arh + kk * 32);
                f16x8 al = *(const f16x8*)(arl + kk * 32);
                accr = __builtin_amdgcn_mfma_f32_16x16x32_f16(ah, br[kk], accr, 0, 0, 0);
                accr = __builtin_amdgcn_mfma_f32_16x16x32_f16(al, br[kk], accr, 0, 0, 0);
                accz = __builtin_amdgcn_mfma_f32_16x16x32_f16(ah, bz[kk], accz, 0, 0, 0);
                accz = __builtin_amdgcn_mfma_f32_16x16x32_f16(al, bz[kk], accz, 0, 0, 0);
                acchn = __builtin_amdgcn_mfma_f32_16x16x32_f16(ah, bn[kk], acchn, 0, 0, 0);
                acchn = __builtin_amdgcn_mfma_f32_16x16x32_f16(al, bn[kk], acchn, 0, 0, 0);
            }
#pragma unroll
            for (int kk = 16; kk < 20; ++kk) {
                f16x8 ah = *(const f16x8*)(arh + 512 + (kk - 16) * 32);
                f16x8 al = *(const f16x8*)(arl + 512 + (kk - 16) * 32);
                accr = __builtin_amdgcn_mfma_f32_16x16x32_f16(ah, br[kk], accr, 0, 0, 0);
                accr = __builtin_amdgcn_mfma_f32_16x16x32_f16(al, br[kk], accr, 0, 0, 0);
                accz = __builtin_amdgcn_mfma_f32_16x16x32_f16(ah, bz[kk], accz, 0, 0, 0);
                accz = __builtin_amdgcn_mfma_f32_16x16x32_f16(al, bz[kk], accz, 0, 0, 0);
                accxn = __builtin_amdgcn_mfma_f32_16x16x32_f16(ah, bn[kk], accxn, 0, 0, 0);
                accxn = __builtin_amdgcn_mfma_f32_16x16x32_f16(al, bn[kk], accxn, 0, 0, 0);
            }

            // ---- gates + state update + packed h stores ----
            unsigned* hwp = hbuf + ((size_t)((1 - par) * 2 + d) * B_ + b0) * H_;
            float yv[4];
            int so4[4];
#pragma unroll
            for (int i = 0; i < 4; ++i) {
                int bl = quad * 4 + i;
                float r = sigm(accr[i] + bias_r);
                float zg = sigm(accz[i] + bias_z);
                float ng = tanhf_((accxn[i] + bihn) + r * (acchn[i] + bhhn));
                float hcand = (1.0f - zg) * ng + zg * h_own[i];
                bool m = (t < len4[i]);
                yv[i] = m ? hcand : 0.0f;
                h_own[i] = m ? hcand : h_own[i];
                _Float16 hhi = (_Float16)h_own[i];
                _Float16 hlo = (_Float16)(h_own[i] - (float)hhi);
                unsigned packed = (unsigned)f16bits(hhi) | ((unsigned)f16bits(hlo) << 16);
                __hip_atomic_store(hwp + (size_t)bl * H_ + j0w + col, packed,
                                   __ATOMIC_RELAXED, __HIP_MEMORY_SCOPE_AGENT);
                so4[i] = (d && m) ? (len4[i] - 1 - t) : t;
            }
            __syncthreads();  // each wave: vmcnt(0) first -> all h stores acked
            if (tid == 0)
                __hip_atomic_store(&slots[(chain * 8 + blk) * 32], (unsigned)(t + 1),
                                   __ATOMIC_RELEASE, __HIP_MEMORY_SCOPE_AGENT);
            // ---- Ycat stores AFTER arrival: drain overlaps next step's spin ----
#pragma unroll
            for (int i = 0; i < 4; ++i) {
                int bl = quad * 4 + i;
                Ycat[((size_t)(b0 + bl) * S_ + so4[i]) * 1024 + d * 512 + j0w + col] =
                    (_Float16)yv[i];
            }
        } else {
            // whole group masked: zeros at s_out = t; no barrier traffic
#pragma unroll
            for (int i = 0; i < 4; ++i) {
                int bl = quad * 4 + i;
                Ycat[((size_t)(b0 + bl) * S_ + t) * 1024 + d * 512 + j0w + col] = (_Float16)0.0f;
            }
        }
    }
}

// Final linear: out[b,s,l] = b_lin[l] + sum_c Ycat[b,s,c] * Wf[l,c]  (fp32 out)
__global__ void lin_kernel(const _Float16* __restrict__ Ycat, const float* __restrict__ Wf,
                           const float* __restrict__ blinF, float* __restrict__ out) {
    int tid = threadIdx.x;
    int p_loc = tid >> 4, lq = tid & 15;
    int pos = blockIdx.x * 16 + p_loc;
    const _Float16* yrow = Ycat + (size_t)pos * 1024;
    int l0 = lq * 4;
    const float* w0 = Wf + (size_t)(l0 + 0) * 1024;
    const float* w1 = Wf + (size_t)(l0 + 1) * 1024;
    const float* w2 = Wf + (size_t)(l0 + 2) * 1024;
    const float* w3 = Wf + (size_t)(l0 + 3) * 1024;
    float a0 = 0.f, a1 = 0.f, a2 = 0.f, a3 = 0.f;
    for (int c = 0; c < 1024; c += 8) {
        f16x8 y8 = *(const f16x8*)(yrow + c);
#pragma unroll
        for (int e = 0; e < 8; ++e) {
            float y = (float)y8[e];
            a0 = fmaf(y, w0[c + e], a0);
            a1 = fmaf(y, w1[c + e], a1);
            a2 = fmaf(y, w2[c + e], a2);
            a3 = fmaf(y, w3[c + e], a3);
        }
    }
    size_t ob = (size_t)pos * L_ + l0;
    out[ob + 0] = a0 + blinF[l0 + 0];
    out[ob + 1] = a1 + blinF[l0 + 1];
    out[ob + 2] = a2 + blinF[l0 + 2];
    out[ob + 3] = a3 + blinF[l0 + 3];
}

extern "C" void kernel_launch(void* const* d_in, const int* in_sizes, int n_in,
                              void* d_out, int out_size, void* d_ws, size_t ws_size,
                              hipStream_t stream) {
    const int* chars = (const int*)d_in[0];
    const int* lengths = (const int*)d_in[1];
    const void* forget = d_in[2];
    const void* Wihf = d_in[3];
    const void* Whhf = d_in[4];
    const void* bihf = d_in[5];
    const void* bhhf = d_in[6];
    const void* Wihb = d_in[7];
    const void* Whhb = d_in[8];
    const void* bihb = d_in[9];
    const void* bhhb = d_in[10];
    const void* Wlin = d_in[11];
    const void* blin = d_in[12];
    float* out = (float*)d_out;

    char* ws = (char*)d_ws;
    unsigned* hbuf = (unsigned*)(ws + 0);
    unsigned* slots = (unsigned*)(ws + OFF_SLOT);
    int* flag = (int*)(ws + OFF_FLAG);
    unsigned short* xhi = (unsigned short*)(ws + OFF_XHI);
    unsigned short* xlo = (unsigned short*)(ws + OFF_XLO);
    _Float16* whalf = (_Float16*)(ws + OFF_WH);
    float* smallF = (float*)(ws + OFF_SMALL);
    _Float16* Ycat = (_Float16*)(ws + OFF_YCAT);

    // zero h state (both parities) + slots + flag
    (void)hipMemsetAsync(ws, 0, OFF_XHI, stream);

    hipLaunchKernelGGL(detect_kernel, dim3(1), dim3(256), 0, stream,
                       (const unsigned*)Whhf, flag);
    hipLaunchKernelGGL(prep_whalf, dim3(1966080 / 256), dim3(256), 0, stream,
                       Whhf, Whhb, Wihf, Wihb, whalf, flag);
    hipLaunchKernelGGL(prep_small, dim3(281), dim3(256), 0, stream,
                       bihf, bhhf, bihb, bhhb, Wlin, blin, forget, smallF, flag);
    hipLaunchKernelGGL(fofe_kernel, dim3(B_ * S_ / 2), dim3(256), 0, stream,
                       chars, smallF + 71744, xhi, xlo);

    // 16 chains x 8 blocks x 256 threads; slot barrier (stores, no RMW).
    hipLaunchKernelGGL(gru_kernel, dim3(128), dim3(256), 0, stream,
                       lengths, whalf, smallF, xhi, xlo, hbuf, slots, Ycat);

    hipLaunchKernelGGL(lin_kernel, dim3(B_ * S_ / 16), dim3(256), 0, stream,
                       Ycat, smallF + 6144, smallF + 71680, out);
}

// Round 10
// 857.561 us; speedup vs baseline: 2.0032x; 1.4965x over previous
//
#include <hip/hip_runtime.h>
#include <hip/hip_bf16.h>

// Problem constants
#define B_ 128
#define S_ 128
#define W_ 16
#define V_ 128
#define H_ 512
#define L_ 64

typedef _Float16 f16x8 __attribute__((ext_vector_type(8)));
typedef float f32x4 __attribute__((ext_vector_type(4)));

__device__ __forceinline__ float sigm(float v) { return 1.0f / (1.0f + __expf(-v)); }
__device__ __forceinline__ float tanhf_(float v) { return 1.0f - 2.0f / (1.0f + __expf(2.0f * v)); }

__device__ __forceinline__ unsigned short f16bits(_Float16 h) {
    return __builtin_bit_cast(unsigned short, h);
}

// ---------------------------------------------------------------------------
// Workspace layout (bytes):
//   hbuf  u32 packed(hi,lo) [par2][dir2][128][512] @ 0        (1048576)
//   slots u32 [16 chains][8 blocks][32 pad]        @ 1048576  (16384)
//   flag  i32                                      @ 1064960  (64)
//   xhi   u16 [128][128][128]                      @ 1065024  (4194304)
//   xlo   u16 [128][128][128]                      @ 5259328  (4194304)
//   whalf f16 [1966080]                            @ 9453632  (3932160)
//         [whhf 786432 | whhb 786432 | wihf 196608 | wihb 196608]
//   smallF f32 [71745]                             @ 13385792 (287040)
//         [bihf 1536|bhhf 1536|bihb 1536|bhhb 1536|wlin 65536|blin 64|fg 1]
//   Ycat  f16 [128][128][1024]                     @ 13672832 (33554432)
//   wlinh f16 [64][1024]                           @ 47227264 (131072)
//   wlinl f16 [64][1024]                           @ 47358336 (131072) -> ends 47489408
// ---------------------------------------------------------------------------
#define OFF_SLOT  1048576
#define OFF_FLAG  1064960
#define OFF_XHI   1065024
#define OFF_XLO   5259328
#define OFF_WH    9453632
#define OFF_SMALL 13385792
#define OFF_YCAT  13672832
#define OFF_WLH   47227264
#define OFF_WLL   47358336

// Runtime input-dtype detection (insurance): low-16 exponent-field vote.
__global__ void detect_kernel(const unsigned* __restrict__ w, int* __restrict__ flag) {
    __shared__ int sv[256];
    int tid = threadIdx.x;
    unsigned word = w[tid];
    unsigned e = (word >> 7) & 0xFFu;
    sv[tid] = (e >= 64u && e <= 126u) ? 1 : 0;
    __syncthreads();
    for (int s = 128; s > 0; s >>= 1) {
        if (tid < s) sv[tid] += sv[tid + s];
        __syncthreads();
    }
    if (tid == 0) *flag = (sv[0] >= 160) ? 1 : 0;  // 1 = inputs are bf16
}

// Canonicalize the 4 big weight matrices into packed fp16 (RTN) in ws.
__global__ void prep_whalf(const void* __restrict__ whhf, const void* __restrict__ whhb,
                           const void* __restrict__ wihf, const void* __restrict__ wihb,
                           _Float16* __restrict__ dst, const int* __restrict__ flag) {
    int i = blockIdx.x * 256 + threadIdx.x;  // grid covers 1966080 exactly
    const void* src;
    int off;
    if (i < 786432)       { src = whhf; off = i; }
    else if (i < 1572864) { src = whhb; off = i - 786432; }
    else if (i < 1769472) { src = wihf; off = i - 1572864; }
    else                  { src = wihb; off = i - 1769472; }
    float v = (*flag) ? __bfloat162float(((const __hip_bfloat16*)src)[off])
                      : ((const float*)src)[off];
    dst[i] = (_Float16)v;
}

// Canonicalize biases + W_lin + b_lin + forget into fp32 in ws.
__global__ void prep_small(const void* __restrict__ bihf, const void* __restrict__ bhhf,
                           const void* __restrict__ bihb, const void* __restrict__ bhhb,
                           const void* __restrict__ wlin, const void* __restrict__ blin,
                           const void* __restrict__ fg,
                           float* __restrict__ dst, const int* __restrict__ flag) {
    int i = blockIdx.x * 256 + threadIdx.x;
    if (i >= 71745) return;
    const void* src;
    int off;
    if (i < 1536)       { src = bihf; off = i; }
    else if (i < 3072)  { src = bhhf; off = i - 1536; }
    else if (i < 4608)  { src = bihb; off = i - 3072; }
    else if (i < 6144)  { src = bhhb; off = i - 4608; }
    else if (i < 71680) { src = wlin; off = i - 6144; }
    else if (i < 71744) { src = blin; off = i - 71680; }
    else                { src = fg;   off = 0; }
    float v = (*flag) ? __bfloat162float(((const __hip_bfloat16*)src)[off])
                      : ((const float*)src)[off];
    dst[i] = v;
}

// W_lin -> hi/lo f16 planes (hi + lo reproduces fp32 to ~2^-22).
__global__ void prep_wlin(const void* __restrict__ wlin,
                          _Float16* __restrict__ whi, _Float16* __restrict__ wlo,
                          const int* __restrict__ flag) {
    int i = blockIdx.x * 256 + threadIdx.x;  // 65536
    float v = (*flag) ? __bfloat162float(((const __hip_bfloat16*)wlin)[i])
                      : ((const float*)wlin)[i];
    _Float16 hi = (_Float16)v;
    whi[i] = hi;
    wlo[i] = (_Float16)(v - (float)hi);
}

// FOFE -> split hi/lo fp16 planes. 256 thr = 2 positions per block.
__global__ void fofe_kernel(const int* __restrict__ chars,
                            const float* __restrict__ fg,
                            unsigned short* __restrict__ xhi,
                            unsigned short* __restrict__ xlo) {
    __shared__ int cS[2][W_];
    int tid = threadIdx.x;
    int sub = tid >> 7;        // 0..1
    int v = tid & 127;
    int bi = blockIdx.x * 2 + sub;  // b*S + s
    if (v < W_) cS[sub][v] = chars[bi * W_ + v];
    __syncthreads();
    float f = fg[0];
    float wt[W_];
    float cur = 1.0f;
#pragma unroll
    for (int w = W_ - 1; w >= 0; --w) {
        bool m = (cS[sub][w] != 0);
        wt[w] = m ? cur : 0.0f;
        if (m) cur *= f;
    }
    float acc = 0.0f;
#pragma unroll
    for (int w = 0; w < W_; ++w) acc += (cS[sub][w] == v) ? wt[w] : 0.0f;
    _Float16 hi = (_Float16)acc;
    _Float16 lo = (_Float16)(acc - (float)hi);
    xhi[(size_t)bi * V_ + v] = f16bits(hi);
    xlo[(size_t)bi * V_ + v] = f16bits(lo);
}

// ---------------------------------------------------------------------------
// Persistent bidirectional GRU — UNCHANGED from round 9 (775us, passing).
// ---------------------------------------------------------------------------
__launch_bounds__(256, 1)
__global__ void gru_kernel(const int* __restrict__ lengths,
                           const _Float16* __restrict__ wh,
                           const float* __restrict__ biasF,
                           const unsigned short* __restrict__ xhi,
                           const unsigned short* __restrict__ xlo,
                           unsigned* __restrict__ hbuf,
                           unsigned* __restrict__ slots,
                           _Float16* __restrict__ Ycat) {
    constexpr int RSTR = 656;  // 640 + 16 pad halves (0 conflicts measured r5/r7)
    __shared__ _Float16 Ahi[16 * RSTR];
    __shared__ _Float16 Alo[16 * RSTR];
    __shared__ int lenS[16];

    const int tid = threadIdx.x;
    const int chain = blockIdx.x & 15;
    const int blk = blockIdx.x >> 4;    // 0..7
    const int d = chain & 1;
    const int bg = chain >> 1;
    const int b0 = bg * 16;
    const int wave = tid >> 6;          // 0..3
    const int lane = tid & 63;
    const int quad = lane >> 4;
    const int col = lane & 15;
    const int j0w = (blk * 4 + wave) * 16;  // 0..496

    const _Float16* Whh = wh + (d ? 786432 : 0);
    const _Float16* Wih = wh + 1572864 + (d ? 196608 : 0);
    const float* bih = biasF + (d ? 3072 : 0);
    const float* bhh = biasF + 1536 + (d ? 3072 : 0);

    if (tid < 16) lenS[tid] = lengths[b0 + tid];
    __syncthreads();

    const int g_r = j0w + col;  // r row; z = 512+g_r; n = 1024+g_r

    // Persistent B fragments: lane holds W[g][kk*32 + quad*8 + 0..7]
    f16x8 br[20], bz[20], bn[20];
#pragma unroll
    for (int kk = 0; kk < 16; ++kk) {
        int k = kk * 32 + quad * 8;
        br[kk] = *(const f16x8*)(Whh + (size_t)(g_r)*H_ + k);
        bz[kk] = *(const f16x8*)(Whh + (size_t)(512 + g_r) * H_ + k);
        bn[kk] = *(const f16x8*)(Whh + (size_t)(1024 + g_r) * H_ + k);
    }
#pragma unroll
    for (int kk = 16; kk < 20; ++kk) {
        int k = (kk - 16) * 32 + quad * 8;
        br[kk] = *(const f16x8*)(Wih + (size_t)(g_r)*V_ + k);
        bz[kk] = *(const f16x8*)(Wih + (size_t)(512 + g_r) * V_ + k);
        bn[kk] = *(const f16x8*)(Wih + (size_t)(1024 + g_r) * V_ + k);
    }

    const float bias_r = bih[g_r] + bhh[g_r];
    const float bias_z = bih[512 + g_r] + bhh[512 + g_r];
    const float bihn = bih[1024 + g_r];
    const float bhhn = bhh[1024 + g_r];

    int len4[4];
#pragma unroll
    for (int i = 0; i < 4; ++i) len4[i] = lenS[quad * 4 + i];
    const int maxlen = lenS[0];  // lengths sorted descending

    float h_own[4] = {0.f, 0.f, 0.f, 0.f};  // fp32 master state (b=quad*4+i, j=col)

    const _Float16* arh = &Ahi[col * RSTR + quad * 8];
    const _Float16* arl = &Alo[col * RSTR + quad * 8];

    // x staging: 16 rows x 16 chunks of 8 halves (int4 per plane per thread)
    const int xb = tid >> 4;
    const int xv8 = (tid & 15) * 8;

    for (int t = 0; t < S_; ++t) {
        if (t < maxlen) {
            const int par = t & 1;
            // ---- x loads (plain cached, RO; issued before barrier) ----
            int lxb = lenS[xb];
            int sxb = d ? max(0, lxb - 1 - t) : t;
            int4 xh4 = *(const int4*)(xhi + ((size_t)(b0 + xb) * S_ + sxb) * V_ + xv8);
            int4 xl4 = *(const int4*)(xlo + ((size_t)(b0 + xb) * S_ + sxb) * V_ + xv8);
            // ---- chain barrier: all 8 blocks posted step t-1 (parallel poll) ----
            if (t > 0) {
                if (tid < 64) {
                    unsigned spins = 0;
                    while (true) {
                        unsigned v = (unsigned)t;
                        if (lane < 8)
                            v = __hip_atomic_load(&slots[(chain * 8 + lane) * 32],
                                                  __ATOMIC_ACQUIRE, __HIP_MEMORY_SCOPE_AGENT);
                        if (__all(v >= (unsigned)t)) break;
                        __builtin_amdgcn_s_sleep(1);
                        if (++spins > 50000000u) break;  // deadlock -> visible timeout
                    }
                }
                __syncthreads();  // join spin; also WAR (step t-1 LDS reads done)
            }
            // ---- h loads: cache-bypass u64 atomics (2 packed elems each) ----
            const unsigned* hrp = hbuf + ((size_t)(par * 2 + d) * B_ + b0) * H_;
            unsigned long long hv[16];
#pragma unroll
            for (int i = 0; i < 16; ++i) {
                int c = tid + i * 256;
                int b = c >> 8;
                int k2 = (c & 255) * 2;
                hv[i] = __hip_atomic_load((const unsigned long long*)(hrp + (size_t)b * H_ + k2),
                                          __ATOMIC_RELAXED, __HIP_MEMORY_SCOPE_AGENT);
            }
            // ---- stage x into LDS (values ready from pre-barrier loads) ----
            *(int4*)&Ahi[xb * RSTR + 512 + xv8] = xh4;
            *(int4*)&Alo[xb * RSTR + 512 + xv8] = xl4;
            // ---- unpack h and stage into LDS ----
#pragma unroll
            for (int i = 0; i < 16; ++i) {
                int c = tid + i * 256;
                int b = c >> 8;
                int k2 = (c & 255) * 2;
                unsigned p0 = (unsigned)hv[i];
                unsigned p1 = (unsigned)(hv[i] >> 32);
                unsigned hi2 = (p0 & 0xffffu) | (p1 << 16);
                unsigned lo2 = (p0 >> 16) | (p1 & 0xffff0000u);
                *(unsigned*)&Ahi[b * RSTR + k2] = hi2;
                *(unsigned*)&Alo[b * RSTR + k2] = lo2;
            }
            __syncthreads();

            // ---- MFMA: hw = (h_hi + h_lo) @ W^T (fp16 in, fp32 acc) ----
            f32x4 accr = {0.f, 0.f, 0.f, 0.f};
            f32x4 accz = {0.f, 0.f, 0.f, 0.f};
            f32x4 acchn = {0.f, 0.f, 0.f, 0.f};
            f32x4 accxn = {0.f, 0.f, 0.f, 0.f};
#pragma unroll
            for (int kk = 0; kk < 16; ++kk) {
                f16x8 ah = *(const f16x8*)(arh + kk * 32);
                f16x8 al = *(const f16x8*)(arl + kk * 32);
                accr = __builtin_amdgcn_mfma_f32_16x16x32_f16(ah, br[kk], accr, 0, 0, 0);
                accr = __builtin_amdgcn_mfma_f32_16x16x32_f16(al, br[kk], accr, 0, 0, 0);
                accz = __builtin_amdgcn_mfma_f32_16x16x32_f16(ah, bz[kk], accz, 0, 0, 0);
                accz = __builtin_amdgcn_mfma_f32_16x16x32_f16(al, bz[kk], accz, 0, 0, 0);
                acchn = __builtin_amdgcn_mfma_f32_16x16x32_f16(ah, bn[kk], acchn, 0, 0, 0);
                acchn = __builtin_amdgcn_mfma_f32_16x16x32_f16(al, bn[kk], acchn, 0, 0, 0);
            }
#pragma unroll
            for (int kk = 16; kk < 20; ++kk) {
                f16x8 ah = *(const f16x8*)(arh + 512 + (kk - 16) * 32);
                f16x8 al = *(const f16x8*)(arl + 512 + (kk - 16) * 32);
                accr = __builtin_amdgcn_mfma_f32_16x16x32_f16(ah, br[kk], accr, 0, 0, 0);
                accr = __builtin_amdgcn_mfma_f32_16x16x32_f16(al, br[kk], accr, 0, 0, 0);
                accz = __builtin_amdgcn_mfma_f32_16x16x32_f16(ah, bz[kk], accz, 0, 0, 0);
                accz = __builtin_amdgcn_mfma_f32_16x16x32_f16(al, bz[kk], accz, 0, 0, 0);
                accxn = __builtin_amdgcn_mfma_f32_16x16x32_f16(ah, bn[kk], accxn, 0, 0, 0);
                accxn = __builtin_amdgcn_mfma_f32_16x16x32_f16(al, bn[kk], accxn, 0, 0, 0);
            }

            // ---- gates + state update + packed h stores ----
            unsigned* hwp = hbuf + ((size_t)((1 - par) * 2 + d) * B_ + b0) * H_;
            float yv[4];
            int so4[4];
#pragma unroll
            for (int i = 0; i < 4; ++i) {
                int bl = quad * 4 + i;
                float r = sigm(accr[i] + bias_r);
                float zg = sigm(accz[i] + bias_z);
                float ng = tanhf_((accxn[i] + bihn) + r * (acchn[i] + bhhn));
                float hcand = (1.0f - zg) * ng + zg * h_own[i];
                bool m = (t < len4[i]);
                yv[i] = m ? hcand : 0.0f;
                h_own[i] = m ? hcand : h_own[i];
                _Float16 hhi = (_Float16)h_own[i];
                _Float16 hlo = (_Float16)(h_own[i] - (float)hhi);
                unsigned packed = (unsigned)f16bits(hhi) | ((unsigned)f16bits(hlo) << 16);
                __hip_atomic_store(hwp + (size_t)bl * H_ + j0w + col, packed,
                                   __ATOMIC_RELAXED, __HIP_MEMORY_SCOPE_AGENT);
                so4[i] = (d && m) ? (len4[i] - 1 - t) : t;
            }
            __syncthreads();  // each wave: vmcnt(0) first -> all h stores acked
            if (tid == 0)
                __hip_atomic_store(&slots[(chain * 8 + blk) * 32], (unsigned)(t + 1),
                                   __ATOMIC_RELEASE, __HIP_MEMORY_SCOPE_AGENT);
            // ---- Ycat stores AFTER arrival: drain overlaps next step's spin ----
#pragma unroll
            for (int i = 0; i < 4; ++i) {
                int bl = quad * 4 + i;
                Ycat[((size_t)(b0 + bl) * S_ + so4[i]) * 1024 + d * 512 + j0w + col] =
                    (_Float16)yv[i];
            }
        } else {
            // whole group masked: zeros at s_out = t; no barrier traffic
#pragma unroll
            for (int i = 0; i < 4; ++i) {
                int bl = quad * 4 + i;
                Ycat[((size_t)(b0 + bl) * S_ + t) * 1024 + d * 512 + j0w + col] = (_Float16)0.0f;
            }
        }
    }
}

// ---------------------------------------------------------------------------
// Final linear as MFMA GEMM: out[pos,l] = blin[l] + sum_c Y[pos,c]*W[l,c].
// [16384 x 1024] x [1024 x 64]. Block = 256 thr (4 waves), covers 64 pos;
// wave covers 16 pos x 64 l (4 n-tiles). A-frags load directly from Ycat
// (f16x8, layout = verified GRU operand pattern); W as hi/lo f16 planes
// (exact fp32 reconstruction). 256 MFMA/wave; grid 256.
// ---------------------------------------------------------------------------
__launch_bounds__(256, 1)
__global__ void lin_kernel(const _Float16* __restrict__ Ycat,
                           const _Float16* __restrict__ Whi,
                           const _Float16* __restrict__ Wlo,
                           const float* __restrict__ blinF,
                           float* __restrict__ out) {
    const int tid = threadIdx.x;
    const int wave = tid >> 6;
    const int lane = tid & 63;
    const int quad = lane >> 4;
    const int col = lane & 15;
    const int pos0 = blockIdx.x * 64 + wave * 16;

    const _Float16* arow = Ycat + (size_t)(pos0 + col) * 1024 + quad * 8;

    f32x4 acc[4] = {{0.f, 0.f, 0.f, 0.f}, {0.f, 0.f, 0.f, 0.f},
                    {0.f, 0.f, 0.f, 0.f}, {0.f, 0.f, 0.f, 0.f}};
#pragma unroll 4
    for (int c = 0; c < 1024; c += 32) {
        f16x8 a = *(const f16x8*)(arow + c);
#pragma unroll
        for (int nt = 0; nt < 4; ++nt) {
            const size_t wo = (size_t)(nt * 16 + col) * 1024 + c + quad * 8;
            f16x8 bh = *(const f16x8*)(Whi + wo);
            f16x8 bl = *(const f16x8*)(Wlo + wo);
            acc[nt] = __builtin_amdgcn_mfma_f32_16x16x32_f16(a, bh, acc[nt], 0, 0, 0);
            acc[nt] = __builtin_amdgcn_mfma_f32_16x16x32_f16(a, bl, acc[nt], 0, 0, 0);
        }
    }
    // C layout: row = quad*4 + reg (pos), col = lane&15 (l within n-tile)
#pragma unroll
    for (int nt = 0; nt < 4; ++nt) {
        int l = nt * 16 + col;
        float bias = blinF[l];
#pragma unroll
        for (int r = 0; r < 4; ++r) {
            int pos = pos0 + quad * 4 + r;
            out[(size_t)pos * L_ + l] = acc[nt][r] + bias;
        }
    }
}

extern "C" void kernel_launch(void* const* d_in, const int* in_sizes, int n_in,
                              void* d_out, int out_size, void* d_ws, size_t ws_size,
                              hipStream_t stream) {
    const int* chars = (const int*)d_in[0];
    const int* lengths = (const int*)d_in[1];
    const void* forget = d_in[2];
    const void* Wihf = d_in[3];
    const void* Whhf = d_in[4];
    const void* bihf = d_in[5];
    const void* bhhf = d_in[6];
    const void* Wihb = d_in[7];
    const void* Whhb = d_in[8];
    const void* bihb = d_in[9];
    const void* bhhb = d_in[10];
    const void* Wlin = d_in[11];
    const void* blin = d_in[12];
    float* out = (float*)d_out;

    char* ws = (char*)d_ws;
    unsigned* hbuf = (unsigned*)(ws + 0);
    unsigned* slots = (unsigned*)(ws + OFF_SLOT);
    int* flag = (int*)(ws + OFF_FLAG);
    unsigned short* xhi = (unsigned short*)(ws + OFF_XHI);
    unsigned short* xlo = (unsigned short*)(ws + OFF_XLO);
    _Float16* whalf = (_Float16*)(ws + OFF_WH);
    float* smallF = (float*)(ws + OFF_SMALL);
    _Float16* Ycat = (_Float16*)(ws + OFF_YCAT);
    _Float16* wlh = (_Float16*)(ws + OFF_WLH);
    _Float16* wll = (_Float16*)(ws + OFF_WLL);

    // zero h state (both parities) + slots + flag
    (void)hipMemsetAsync(ws, 0, OFF_XHI, stream);

    hipLaunchKernelGGL(detect_kernel, dim3(1), dim3(256), 0, stream,
                       (const unsigned*)Whhf, flag);
    hipLaunchKernelGGL(prep_whalf, dim3(1966080 / 256), dim3(256), 0, stream,
                       Whhf, Whhb, Wihf, Wihb, whalf, flag);
    hipLaunchKernelGGL(prep_small, dim3(281), dim3(256), 0, stream,
                       bihf, bhhf, bihb, bhhb, Wlin, blin, forget, smallF, flag);
    hipLaunchKernelGGL(prep_wlin, dim3(256), dim3(256), 0, stream,
                       Wlin, wlh, wll, flag);
    hipLaunchKernelGGL(fofe_kernel, dim3(B_ * S_ / 2), dim3(256), 0, stream,
                       chars, smallF + 71744, xhi, xlo);

    // 16 chains x 8 blocks x 256 threads; slot barrier (stores, no RMW).
    hipLaunchKernelGGL(gru_kernel, dim3(128), dim3(256), 0, stream,
                       lengths, whalf, smallF, xhi, xlo, hbuf, slots, Ycat);

    // MFMA GEMM epilogue: 256 blocks x 64 pos.
    hipLaunchKernelGGL(lin_kernel, dim3(256), dim3(256), 0, stream,
                       Ycat, wlh, wll, smallF + 71680, out);
}